// Round 1
// baseline (633.766 us; speedup 1.0000x reference)
//
#include <hip/hip_runtime.h>

constexpr int TT = 2048;
constexpr int CC = 1024;
constexpr int DH = 64;
constexpr float SCALE = 0.03125f;  // 1/sqrt(1024)

// ---------------- Kernel 1: fused QKV projection ----------------
// grid 512 × 256 thr; block computes 32 rows × 192 cols (K|Q|V).
// Thread: tx=tid&31 -> cols 6*tx..6*tx+5 ; ty=tid>>5 -> rows 4*ty..4*ty+3
__global__ __launch_bounds__(256, 2)
void qkv_proj_kernel(const float* __restrict__ x,
                     const float* __restrict__ Wk,
                     const float* __restrict__ Wq,
                     const float* __restrict__ Wv,
                     float* __restrict__ kO,
                     float* __restrict__ qO,
                     float* __restrict__ vO)
{
    __shared__ float xs[32][64];    // [row][k]  (reads are 2-way broadcast)
    __shared__ float ws[64][192];   // [k][col]  col = m*64+d, m in {K,Q,V}

    const int tid = threadIdx.x;
    const int tx = tid & 31;
    const int ty = tid >> 5;
    const int row0 = blockIdx.x * 32;
    const int c0 = tx * 6;

    float acc[4][6];
    #pragma unroll
    for (int i = 0; i < 4; ++i)
        #pragma unroll
        for (int j = 0; j < 6; ++j) acc[i][j] = 0.f;

    for (int kc = 0; kc < CC; kc += 64) {
        __syncthreads();
        // stage x tile: 32x64 floats, coalesced float4
        #pragma unroll
        for (int i = 0; i < 2; ++i) {
            int g = tid + 256 * i;
            int r = g >> 4, k4 = g & 15;
            *(float4*)&xs[r][k4 * 4] =
                *(const float4*)&x[(size_t)(row0 + r) * CC + kc + k4 * 4];
        }
        // stage W tile: 64x192 floats (Wk|Wq|Wv rows), coalesced float4
        #pragma unroll
        for (int i = 0; i < 12; ++i) {
            int g = tid + 256 * i;
            int k = g / 48, c4 = g % 48;
            int m = c4 >> 4, d4 = c4 & 15;
            const float* wp = (m == 0) ? Wk : (m == 1) ? Wq : Wv;
            *(float4*)&ws[k][c4 * 4] =
                *(const float4*)&wp[(size_t)(kc + k) * DH + d4 * 4];
        }
        __syncthreads();

        #pragma unroll
        for (int k4 = 0; k4 < 16; ++k4) {
            float4 xv[4];
            #pragma unroll
            for (int i = 0; i < 4; ++i)
                xv[i] = *(const float4*)&xs[ty * 4 + i][k4 * 4];
            #pragma unroll
            for (int u = 0; u < 4; ++u) {
                int k = k4 * 4 + u;
                float2 w01 = *(const float2*)&ws[k][c0];
                float2 w23 = *(const float2*)&ws[k][c0 + 2];
                float2 w45 = *(const float2*)&ws[k][c0 + 4];
                #pragma unroll
                for (int i = 0; i < 4; ++i) {
                    float xu = (&xv[i].x)[u];
                    acc[i][0] = fmaf(xu, w01.x, acc[i][0]);
                    acc[i][1] = fmaf(xu, w01.y, acc[i][1]);
                    acc[i][2] = fmaf(xu, w23.x, acc[i][2]);
                    acc[i][3] = fmaf(xu, w23.y, acc[i][3]);
                    acc[i][4] = fmaf(xu, w45.x, acc[i][4]);
                    acc[i][5] = fmaf(xu, w45.y, acc[i][5]);
                }
            }
        }
    }

    #pragma unroll
    for (int i = 0; i < 4; ++i) {
        int rg = row0 + ty * 4 + i;
        #pragma unroll
        for (int j = 0; j < 6; ++j) {
            int c = c0 + j;
            int m = c >> 6, d = c & 63;
            float val = acc[i][j];
            if (m == 1) val *= SCALE;          // fold 1/sqrt(C) into Q
            float* dst = (m == 0) ? kO : (m == 1) ? qO : vO;
            dst[(size_t)rg * DH + d] = val;
        }
    }
}

// ---------------- Kernel 2: causal flash attention, fp32 ----------------
// grid (64, 8) × 256 thr. Block: 32 q-rows; wave: 8 q-rows. Key tiles of 64.
// QK^T: lane=key, K-row in VGPRs, q via wave-uniform (SGPR) loads.
// PV:   lane=dim, P broadcast from per-wave LDS as float4.
__global__ __launch_bounds__(256, 2)
void attn_kernel(const float* __restrict__ q,
                 const float* __restrict__ k,
                 const float* __restrict__ v,
                 float* __restrict__ out)
{
    constexpr int QB = 32;
    constexpr int RW = 8;
    __shared__ float Ks[64][68];
    __shared__ float Vs[64][68];
    __shared__ float Ps[4][RW][68];

    const int tid = threadIdx.x;
    const int lane = tid & 63;
    const int w = tid >> 6;
    const int b = blockIdx.y;
    const int q0 = blockIdx.x * QB;
    const int nt = (q0 + QB + 63) >> 6;   // key tiles (causal)
    const size_t bo = (size_t)b * TT * DH;

    float m[RW], l[RW], acc[RW];
    #pragma unroll
    for (int r = 0; r < RW; ++r) {
        m[r] = -__builtin_inff(); l[r] = 0.f; acc[r] = 0.f;
    }

    const int rbase = __builtin_amdgcn_readfirstlane(q0 + w * RW);

    for (int kt = 0; kt < nt; ++kt) {
        __syncthreads();
        // stage K,V tiles (64x64 each), coalesced float4
        #pragma unroll
        for (int i = 0; i < 4; ++i) {
            int g = tid + 256 * i;
            int r = g >> 4, d4 = g & 15;
            size_t go = bo + (size_t)(kt * 64 + r) * DH + d4 * 4;
            *(float4*)&Ks[r][d4 * 4] = *(const float4*)&k[go];
            *(float4*)&Vs[r][d4 * 4] = *(const float4*)&v[go];
        }
        __syncthreads();

        // this lane's K row -> registers (conflict-free: stride 68)
        float4 kr[16];
        #pragma unroll
        for (int d4 = 0; d4 < 16; ++d4)
            kr[d4] = *(const float4*)&Ks[lane][d4 * 4];

        const bool bdry = (kt == nt - 1);
        const int jg = kt * 64 + lane;

        #pragma unroll
        for (int r = 0; r < RW; ++r) {
            int rg = rbase + r;
            const float4* qp = (const float4*)&q[bo + (size_t)rg * DH];
            float s0 = 0.f, s1 = 0.f;
            #pragma unroll
            for (int d4 = 0; d4 < 16; d4 += 2) {
                float4 a = kr[d4];     float4 qa = qp[d4];
                float4 b2 = kr[d4 + 1]; float4 qb = qp[d4 + 1];
                s0 = fmaf(a.x, qa.x, s0);  s0 = fmaf(a.y, qa.y, s0);
                s0 = fmaf(a.z, qa.z, s0);  s0 = fmaf(a.w, qa.w, s0);
                s1 = fmaf(b2.x, qb.x, s1); s1 = fmaf(b2.y, qb.y, s1);
                s1 = fmaf(b2.z, qb.z, s1); s1 = fmaf(b2.w, qb.w, s1);
            }
            float s = s0 + s1;                      // scale folded into q
            if (bdry && jg > rg) s = -__builtin_inff();

            float mt = s;
            #pragma unroll
            for (int off = 32; off > 0; off >>= 1)
                mt = fmaxf(mt, __shfl_xor(mt, off));
            float mn = fmaxf(m[r], mt);
            float al = __expf(m[r] - mn);           // 0 on first tile
            m[r] = mn;
            float p = __expf(s - mn);               // 0 on masked lanes
            float ps = p;
            #pragma unroll
            for (int off = 32; off > 0; off >>= 1)
                ps += __shfl_xor(ps, off);
            l[r] = l[r] * al + ps;
            acc[r] *= al;
            Ps[w][r][lane] = p;                     // per-wave region, no barrier
        }

        // PV: lane = output dim
        #pragma unroll
        for (int j0 = 0; j0 < 64; j0 += 16) {
            float vv[16];
            #pragma unroll
            for (int jj = 0; jj < 16; ++jj) vv[jj] = Vs[j0 + jj][lane];
            #pragma unroll
            for (int r = 0; r < RW; ++r) {
                const float4* pp = (const float4*)&Ps[w][r][j0];
                float4 p0 = pp[0], p1 = pp[1], p2 = pp[2], p3 = pp[3];
                acc[r] = fmaf(p0.x, vv[0],  acc[r]);
                acc[r] = fmaf(p0.y, vv[1],  acc[r]);
                acc[r] = fmaf(p0.z, vv[2],  acc[r]);
                acc[r] = fmaf(p0.w, vv[3],  acc[r]);
                acc[r] = fmaf(p1.x, vv[4],  acc[r]);
                acc[r] = fmaf(p1.y, vv[5],  acc[r]);
                acc[r] = fmaf(p1.z, vv[6],  acc[r]);
                acc[r] = fmaf(p1.w, vv[7],  acc[r]);
                acc[r] = fmaf(p2.x, vv[8],  acc[r]);
                acc[r] = fmaf(p2.y, vv[9],  acc[r]);
                acc[r] = fmaf(p2.z, vv[10], acc[r]);
                acc[r] = fmaf(p2.w, vv[11], acc[r]);
                acc[r] = fmaf(p3.x, vv[12], acc[r]);
                acc[r] = fmaf(p3.y, vv[13], acc[r]);
                acc[r] = fmaf(p3.z, vv[14], acc[r]);
                acc[r] = fmaf(p3.w, vv[15], acc[r]);
            }
        }
    }

    #pragma unroll
    for (int r = 0; r < RW; ++r) {
        int rg = rbase + r;
        out[bo + (size_t)rg * DH + lane] = acc[r] / l[r];
    }
}

extern "C" void kernel_launch(void* const* d_in, const int* in_sizes, int n_in,
                              void* d_out, int out_size, void* d_ws, size_t ws_size,
                              hipStream_t stream) {
    const float* x  = (const float*)d_in[0];
    // d_in[1] = eos_mask: deterministic causal tril, applied analytically
    const float* Wk = (const float*)d_in[2];
    const float* Wq = (const float*)d_in[3];
    const float* Wv = (const float*)d_in[4];

    float* kO = (float*)d_ws;                       //  4 MB
    float* qO = kO + (size_t)8 * TT * DH;           //  4 MB
    float* vO = qO + (size_t)8 * TT * DH;           //  4 MB
    float* out = (float*)d_out;

    qkv_proj_kernel<<<dim3(512), dim3(256), 0, stream>>>(x, Wk, Wq, Wv, kO, qO, vO);
    attn_kernel<<<dim3(64, 8), dim3(256), 0, stream>>>(qO, kO, vO, out);
}